// Round 4
// baseline (508.642 us; speedup 1.0000x reference)
//
#include <hip/hip_runtime.h>

typedef unsigned short u16;
typedef __attribute__((ext_vector_type(8))) short short8;
typedef __attribute__((ext_vector_type(4))) float f32x4;

// Problem constants: B=2, T=2048, C=2048, H=16, HD=128
#define TSEQ 2048
#define NHEAD 16
#define HDIM 128

__device__ __forceinline__ u16 f2bf(float x) {
    unsigned u = __float_as_uint(x);
    return (u16)((u + 0x7fffu + ((u >> 16) & 1u)) >> 16);
}
__device__ __forceinline__ float b2f(u16 h) {
    return __uint_as_float(((unsigned)h) << 16);
}
__device__ __forceinline__ void async16(const void* g, void* l) {
    __builtin_amdgcn_global_load_lds((__attribute__((address_space(1))) void*)(void*)g,
                                     (__attribute__((address_space(3))) void*)l, 16, 0, 0);
}
__device__ __forceinline__ f32x4 zero4() {
    f32x4 z = {0.f, 0.f, 0.f, 0.f};
    return z;
}

// DPP cross-lane (16-lane group reductions), no LDS traffic
template <int CTRL>
__device__ __forceinline__ float dppf(float x) {
    return __int_as_float(__builtin_amdgcn_mov_dpp(__float_as_int(x), CTRL, 0xf, 0xf, true));
}
__device__ __forceinline__ float dpp_max16(float x) {
    x = fmaxf(x, dppf<0xB1>(x));   // quad_perm xor1
    x = fmaxf(x, dppf<0x4E>(x));   // quad_perm xor2
    x = fmaxf(x, dppf<0x141>(x));  // row_half_mirror (~xor4)
    x = fmaxf(x, dppf<0x140>(x));  // row_mirror (~xor8)
    return x;
}
__device__ __forceinline__ float dpp_sum16(float x) {
    x += dppf<0xB1>(x);
    x += dppf<0x4E>(x);
    x += dppf<0x141>(x);
    x += dppf<0x140>(x);
    return x;
}

// ---------------- cast x (f32 -> bf16), vectorized ----------------
__global__ void cast_bf16(const float4* __restrict__ in, ushort4* __restrict__ out, int n4) {
    int i = blockIdx.x * 256 + threadIdx.x;
    if (i < n4) {
        float4 v = in[i];
        ushort4 o;
        o.x = f2bf(v.x); o.y = f2bf(v.y); o.z = f2bf(v.z); o.w = f2bf(v.w);
        out[i] = o;
    }
}

// ---------------- transpose + cast: in f32 [K][N] -> out bf16 [N][K] ----------------
__global__ void transpose_cast(const float* __restrict__ in, u16* __restrict__ out, int K, int N) {
    __shared__ float tile[64][65];
    int n0 = blockIdx.x * 64, k0 = blockIdx.y * 64;
    int tx = threadIdx.x & 63, ty = threadIdx.x >> 6;
#pragma unroll
    for (int i = 0; i < 16; i++) {
        int r = ty + i * 4;
        tile[r][tx] = in[(size_t)(k0 + r) * N + n0 + tx];
    }
    __syncthreads();
#pragma unroll
    for (int i = 0; i < 16; i++) {
        int r = ty + i * 4;
        out[(size_t)(n0 + r) * K + k0 + tx] = f2bf(tile[tx][r]);
    }
}

// ---------------- GEMM: C = A(MxK) * Bt(NxK)^T + bias ----------------
// MODE 0: n-tile == one head (HDIM=128). LDS-transpose epilogue, fused RoPE
//         for q/k, v written transposed to vT [bh][d][t].
// MODE 1: f32 out row-major [M][N]
template <int MODE>
__global__ __launch_bounds__(256, 5) void gemm_bt(
    const u16* __restrict__ A, const u16* __restrict__ Bt, const float* __restrict__ bias,
    float* __restrict__ outf, u16* __restrict__ qb, u16* __restrict__ kb, u16* __restrict__ vT,
    const float* __restrict__ cosp, const float* __restrict__ sinp,
    int M, int N, int K) {
    __shared__ __align__(16) u16 smem[8704];  // 17408 B: staging (16K) / epilogue tile [64][136]
    u16* As = smem;            // 128*32 u16
    u16* Bs = smem + 4096;     // 128*32 u16
    const int tid = threadIdx.x;
    const int wave = tid >> 6, lane = tid & 63;
    const int low = lane & 15, quad = lane >> 4;
    const int m0 = blockIdx.y * 128, n0 = blockIdx.x * 128;
    const int wm = (wave >> 1) * 64, wn = (wave & 1) * 64;
    const int ldr = lane >> 2;
    const int ldc = (lane & 3) * 8;

    f32x4 acc[4][4];
#pragma unroll
    for (int i = 0; i < 4; i++)
#pragma unroll
        for (int j = 0; j < 4; j++) acc[i][j] = zero4();

    for (int k0 = 0; k0 < K; k0 += 32) {
#pragma unroll
        for (int c = 0; c < 2; ++c) {
            const int chunk = wave * 2 + c;
            const int row = chunk * 16 + ldr;
            async16(A + (size_t)(m0 + row) * K + k0 + ldc, As + chunk * 512);
            async16(Bt + (size_t)(n0 + row) * K + k0 + ldc, Bs + chunk * 512);
        }
        __syncthreads();
        short8 af[4], bfv[4];
#pragma unroll
        for (int i = 0; i < 4; i++) af[i] = *(const short8*)(As + (wm + i * 16 + low) * 32 + quad * 8);
#pragma unroll
        for (int j = 0; j < 4; j++) bfv[j] = *(const short8*)(Bs + (wn + j * 16 + low) * 32 + quad * 8);
#pragma unroll
        for (int i = 0; i < 4; i++)
#pragma unroll
            for (int j = 0; j < 4; j++)
                acc[i][j] = __builtin_amdgcn_mfma_f32_16x16x32_bf16(af[i], bfv[j], acc[i][j], 0, 0, 0);
        __syncthreads();
    }

    if (MODE == 1) {
#pragma unroll
        for (int j = 0; j < 4; j++) {
            const int ng = n0 + wn + j * 16 + low;
            const float bv = bias[ng];
#pragma unroll
            for (int i = 0; i < 4; i++) {
                const int rbase = m0 + wm + i * 16 + quad * 4;
#pragma unroll
                for (int r = 0; r < 4; r++)
                    outf[(size_t)(rbase + r) * N + ng] = acc[i][j][r] + bv;
            }
        }
        return;
    }

    // ---- MODE 0 epilogue ----
    const int which = n0 >> 11;                // 0=q 1=k 2=v
    const int h = (n0 & 2047) >> 7;
    const int b = m0 >> 11, t0 = m0 & 2047;
    float bv[4];
#pragma unroll
    for (int j = 0; j < 4; j++) bv[j] = bias[n0 + wn + j * 16 + low];
    u16* epi = smem;  // [64][136] bf16

    if (which < 2) {
        // q or k: [bh][t][d] contiguous tile, rope fused
        u16* dst = (which == 0 ? qb : kb) + (((size_t)(b * NHEAD + h)) * TSEQ + t0) * HDIM;
#pragma unroll
        for (int pass = 0; pass < 2; pass++) {
            if ((wave >> 1) == pass) {
#pragma unroll
                for (int i = 0; i < 4; i++)
#pragma unroll
                    for (int j = 0; j < 4; j++)
#pragma unroll
                        for (int r = 0; r < 4; r++)
                            epi[(i * 16 + quad * 4 + r) * 136 + wn + j * 16 + low] =
                                f2bf(acc[i][j][r] + bv[j]);
            }
            __syncthreads();
            const int row = tid >> 2, dq = tid & 3;
            const int t = t0 + pass * 64 + row;
            const float* cb = cosp + (size_t)t * 64 + dq * 16;
            const float* sb = sinp + (size_t)t * 64 + dq * 16;
            const u16* er = epi + row * 136 + dq * 32;
            u16* dr = dst + (size_t)(pass * 64 + row) * HDIM + dq * 32;
#pragma unroll
            for (int half = 0; half < 2; half++) {
                u16 vals[16];
                *(short8*)(vals) = *(const short8*)(er + half * 16);
                *(short8*)(vals + 8) = *(const short8*)(er + half * 16 + 8);
                float cs[8], sn[8];
                *(float4*)(cs) = *(const float4*)(cb + half * 8);
                *(float4*)(cs + 4) = *(const float4*)(cb + half * 8 + 4);
                *(float4*)(sn) = *(const float4*)(sb + half * 8);
                *(float4*)(sn + 4) = *(const float4*)(sb + half * 8 + 4);
                u16 ov[16];
#pragma unroll
                for (int p = 0; p < 8; p++) {
                    float x0 = b2f(vals[2 * p]), x1 = b2f(vals[2 * p + 1]);
                    ov[2 * p] = f2bf(x0 * cs[p] - x1 * sn[p]);
                    ov[2 * p + 1] = f2bf(x0 * sn[p] + x1 * cs[p]);
                }
                *(short8*)(dr + half * 16) = *(const short8*)(ov);
                *(short8*)(dr + half * 16 + 8) = *(const short8*)(ov + 8);
            }
            __syncthreads();
        }
    } else {
        // v: write transposed [bh][d][t]; LDS tile holds [d-rel 64][t 128+pad]
        u16* dst = vT + ((size_t)(b * NHEAD + h)) * HDIM * TSEQ + t0;
#pragma unroll
        for (int pass = 0; pass < 2; pass++) {
            if ((wave & 1) == pass) {  // wn == pass*64
#pragma unroll
                for (int i = 0; i < 4; i++)
#pragma unroll
                    for (int j = 0; j < 4; j++)
#pragma unroll
                        for (int r = 0; r < 4; r++)
                            epi[(j * 16 + low) * 136 + wm + i * 16 + quad * 4 + r] =
                                f2bf(acc[i][j][r] + bv[j]);
            }
            __syncthreads();
            const int drow = tid >> 2, tc = (tid & 3) * 32;
            u16* dr = dst + (size_t)(pass * 64 + drow) * TSEQ + tc;
#pragma unroll
            for (int q = 0; q < 4; q++)
                *(short8*)(dr + q * 8) = *(const short8*)(epi + drow * 136 + tc + q * 8);
            __syncthreads();
        }
    }
}

// ---------------- Flash attention v3: pipelined LDS staging, 128 q-rows/block ----------------
// 4 waves x 2 q-tiles (16 rows each). Per 64-key tile: top barrier (loads from
// prev mid already landed) -> QK both tiles from Ks -> mid barrier -> issue
// K[kt+1]->Ks, V[kt+1]->Vs[buf^1] -> softmax+PV (covers load latency).
__global__ __launch_bounds__(256, 2) void flash_attn(const u16* __restrict__ qg, const u16* __restrict__ kg,
                                                     const u16* __restrict__ vT, u16* __restrict__ y) {
    __shared__ u16 Ks[64 * 128];     // 16 KB [key][d], chunks xor-swizzled by (key&7)
    __shared__ u16 Vs[2][128 * 64];  // 32 KB [d][key], chunks xor-swizzled by (d&7)
    __shared__ u16 Ps[4][16 * 72];   // 9 KB per-wave P 16x64, row stride 72
    const int tid = threadIdx.x;
    const int wave = tid >> 6, lane = tid & 63;
    const int low = lane & 15, quad = lane >> 4;
    const int qt = 15 - blockIdx.x;  // longest blocks dispatch first
    const int bh = blockIdx.y;
    const int qa = qt * 128 + wave * 16;
    const int qbr = qa + 64;
    const float scale2 = 0.08838834764831845f * 1.44269504088896f;  // 1/sqrt(128)*log2(e)

    const u16* Qp = qg + (size_t)bh * TSEQ * HDIM;
    short8 qfA[4], qfB[4];
#pragma unroll
    for (int c = 0; c < 4; c++) {
        qfA[c] = *(const short8*)(Qp + (size_t)(qa + low) * HDIM + c * 32 + quad * 8);
        qfB[c] = *(const short8*)(Qp + (size_t)(qbr + low) * HDIM + c * 32 + quad * 8);
    }

    f32x4 oA[8], oB[8];
#pragma unroll
    for (int d = 0; d < 8; d++) { oA[d] = zero4(); oB[d] = zero4(); }
    float mA[4], lA[4], mB[4], lB[4];
#pragma unroll
    for (int r = 0; r < 4; r++) { mA[r] = -1e30f; lA[r] = 0.f; mB[r] = -1e30f; lB[r] = 0.f; }

    const u16* Kb = kg + (size_t)bh * TSEQ * HDIM;
    const u16* Vb = vT + (size_t)bh * HDIM * TSEQ;
    u16* Pw = &Ps[wave][0];
    const int ntiles = 2 * qt + 2;

    const int krow = tid >> 4, kchunk = tid & 15;  // K: 16 rows x 16 chunks per issue
    const int vrow = tid >> 3, vchunk = tid & 7;   // V: 32 rows x 8 chunks per issue

    // prologue: stage tile 0
#pragma unroll
    for (int j = 0; j < 4; j++) {
        const int row = j * 16 + krow;
        async16(Kb + (size_t)row * HDIM + (kchunk ^ (row & 7)) * 8, Ks + row * 128 + kchunk * 8);
    }
#pragma unroll
    for (int j = 0; j < 4; j++) {
        const int d = j * 32 + vrow;
        async16(Vb + (size_t)d * TSEQ + (vchunk ^ (d & 7)) * 8, Vs[0] + d * 64 + vchunk * 8);
    }

    for (int kt = 0; kt < ntiles; ++kt) {
        const int kv0 = kt * 64;
        const int cur = kt & 1;
        __syncthreads();  // drains loads issued at prev mid-point

        const bool activeA = (kv0 <= qa + 15);
        f32x4 sA[4], sB[4];
#pragma unroll
        for (int h = 0; h < 4; h++) { sA[h] = zero4(); sB[h] = zero4(); }
        if (activeA) {
#pragma unroll
            for (int h = 0; h < 4; h++) {
                const int row = h * 16 + low;
#pragma unroll
                for (int c = 0; c < 4; c++) {
                    short8 kf = *(const short8*)(Ks + row * 128 + (((c * 4 + quad) ^ (row & 7))) * 8);
                    sA[h] = __builtin_amdgcn_mfma_f32_16x16x32_bf16(qfA[c], kf, sA[h], 0, 0, 0);
                }
            }
        }
#pragma unroll
        for (int h = 0; h < 4; h++) {
            const int row = h * 16 + low;
#pragma unroll
            for (int c = 0; c < 4; c++) {
                short8 kf = *(const short8*)(Ks + row * 128 + (((c * 4 + quad) ^ (row & 7))) * 8);
                sB[h] = __builtin_amdgcn_mfma_f32_16x16x32_bf16(qfB[c], kf, sB[h], 0, 0, 0);
            }
        }
        __syncthreads();  // all waves done reading Ks; nothing outstanding -> cheap

        if (kt + 1 < ntiles) {
            const int nkv = kv0 + 64;
#pragma unroll
            for (int j = 0; j < 4; j++) {
                const int row = j * 16 + krow;
                async16(Kb + (size_t)(nkv + row) * HDIM + (kchunk ^ (row & 7)) * 8,
                        Ks + row * 128 + kchunk * 8);
            }
            u16* vdst = Vs[cur ^ 1];
#pragma unroll
            for (int j = 0; j < 4; j++) {
                const int d = j * 32 + vrow;
                async16(Vb + (size_t)d * TSEQ + nkv + (vchunk ^ (d & 7)) * 8, vdst + d * 64 + vchunk * 8);
            }
        }

        const u16* Vcur = Vs[cur];
        // ---- tile A: softmax + PV ----
        if (activeA) {
            float alpha[4];
#pragma unroll
            for (int r = 0; r < 4; r++) {
                const int qrow = qa + quad * 4 + r;
                float sv[4];
#pragma unroll
                for (int h = 0; h < 4; h++)
                    sv[h] = (kv0 + h * 16 + low <= qrow) ? sA[h][r] * scale2 : -1e30f;
                float mx = fmaxf(fmaxf(sv[0], sv[1]), fmaxf(sv[2], sv[3]));
                mx = dpp_max16(mx);
                float mnew = fmaxf(mA[r], mx);
                alpha[r] = exp2f(mA[r] - mnew);
                mA[r] = mnew;
                float p0 = exp2f(sv[0] - mnew), p1 = exp2f(sv[1] - mnew);
                float p2 = exp2f(sv[2] - mnew), p3 = exp2f(sv[3] - mnew);
                float rs = (p0 + p1) + (p2 + p3);
                rs = dpp_sum16(rs);
                lA[r] = lA[r] * alpha[r] + rs;
                const int prow = (quad * 4 + r) * 72;
                Pw[prow + low] = f2bf(p0);
                Pw[prow + 16 + low] = f2bf(p1);
                Pw[prow + 32 + low] = f2bf(p2);
                Pw[prow + 48 + low] = f2bf(p3);
            }
            __threadfence_block();
#pragma unroll
            for (int d = 0; d < 8; ++d)
#pragma unroll
                for (int r = 0; r < 4; r++) oA[d][r] *= alpha[r];
#pragma unroll
            for (int kc = 0; kc < 2; kc++) {
                short8 pf = *(const short8*)(Pw + low * 72 + kc * 32 + quad * 8);
#pragma unroll
                for (int dd = 0; dd < 8; ++dd) {
                    const int vr = dd * 16 + low;
                    short8 vf = *(const short8*)(Vcur + vr * 64 + (((kc * 4 + quad) ^ (vr & 7))) * 8);
                    oA[dd] = __builtin_amdgcn_mfma_f32_16x16x32_bf16(pf, vf, oA[dd], 0, 0, 0);
                }
            }
        }
        // ---- tile B ----
        {
            float alpha[4];
#pragma unroll
            for (int r = 0; r < 4; r++) {
                const int qrow = qbr + quad * 4 + r;
                float sv[4];
#pragma unroll
                for (int h = 0; h < 4; h++)
                    sv[h] = (kv0 + h * 16 + low <= qrow) ? sB[h][r] * scale2 : -1e30f;
                float mx = fmaxf(fmaxf(sv[0], sv[1]), fmaxf(sv[2], sv[3]));
                mx = dpp_max16(mx);
                float mnew = fmaxf(mB[r], mx);
                alpha[r] = exp2f(mB[r] - mnew);
                mB[r] = mnew;
                float p0 = exp2f(sv[0] - mnew), p1 = exp2f(sv[1] - mnew);
                float p2 = exp2f(sv[2] - mnew), p3 = exp2f(sv[3] - mnew);
                float rs = (p0 + p1) + (p2 + p3);
                rs = dpp_sum16(rs);
                lB[r] = lB[r] * alpha[r] + rs;
                const int prow = (quad * 4 + r) * 72;
                Pw[prow + low] = f2bf(p0);
                Pw[prow + 16 + low] = f2bf(p1);
                Pw[prow + 32 + low] = f2bf(p2);
                Pw[prow + 48 + low] = f2bf(p3);
            }
            __threadfence_block();
#pragma unroll
            for (int d = 0; d < 8; ++d)
#pragma unroll
                for (int r = 0; r < 4; r++) oB[d][r] *= alpha[r];
#pragma unroll
            for (int kc = 0; kc < 2; kc++) {
                short8 pf = *(const short8*)(Pw + low * 72 + kc * 32 + quad * 8);
#pragma unroll
                for (int dd = 0; dd < 8; ++dd) {
                    const int vr = dd * 16 + low;
                    short8 vf = *(const short8*)(Vcur + vr * 64 + (((kc * 4 + quad) ^ (vr & 7))) * 8);
                    oB[dd] = __builtin_amdgcn_mfma_f32_16x16x32_bf16(pf, vf, oB[dd], 0, 0, 0);
                }
            }
        }
    }

    const int b = bh >> 4, h = bh & 15;
#pragma unroll
    for (int r = 0; r < 4; r++) {
        float invA = 1.0f / lA[r];
        float invB = 1.0f / lB[r];
        size_t rowA = (size_t)(b * TSEQ + qa + quad * 4 + r);
        size_t rowB = (size_t)(b * TSEQ + qbr + quad * 4 + r);
        u16* ypA = y + rowA * 2048 + h * HDIM;
        u16* ypB = y + rowB * 2048 + h * HDIM;
#pragma unroll
        for (int d = 0; d < 8; ++d) {
            ypA[d * 16 + low] = f2bf(oA[d][r] * invA);
            ypB[d * 16 + low] = f2bf(oB[d][r] * invB);
        }
    }
}

extern "C" void kernel_launch(void* const* d_in, const int* in_sizes, int n_in,
                              void* d_out, int out_size, void* d_ws, size_t ws_size,
                              hipStream_t stream) {
    const float* x = (const float*)d_in[0];
    const float* Wa = (const float*)d_in[1];
    const float* ba = (const float*)d_in[2];
    const float* Wp = (const float*)d_in[3];
    const float* bp = (const float*)d_in[4];
    const float* cs = (const float*)d_in[5];
    const float* sn = (const float*)d_in[6];
    float* out = (float*)d_out;

    u16* xb = (u16*)d_ws;             // x bf16; reused later as y
    u16* Wab = xb + 8388608;          // W_attn^T bf16 [6144][2048]
    u16* Wpb = Wab + 12582912;        // W_proj^T bf16 [2048][2048]
    u16* qb = Wpb + 4194304;          // [bh][t][d]
    u16* kb = qb + 8388608;           // [bh][t][d]
    u16* vT = kb + 8388608;           // [bh][d][t]
    u16* y = xb;

    cast_bf16<<<8192, 256, 0, stream>>>((const float4*)x, (ushort4*)xb, 2097152);
    transpose_cast<<<dim3(96, 32), 256, 0, stream>>>(Wa, Wab, 2048, 6144);
    transpose_cast<<<dim3(32, 32), 256, 0, stream>>>(Wp, Wpb, 2048, 2048);
    gemm_bt<0><<<dim3(48, 32), 256, 0, stream>>>(xb, Wab, ba, nullptr, qb, kb, vT, cs, sn, 4096, 6144, 2048);
    flash_attn<<<dim3(16, 32), 256, 0, stream>>>(qb, kb, vT, y);
    gemm_bt<1><<<dim3(16, 32), 256, 0, stream>>>(y, Wpb, bp, out, nullptr, nullptr, nullptr, nullptr, nullptr, 4096, 2048, 2048);
}

// Round 5
// 468.850 us; speedup vs baseline: 1.0849x; 1.0849x over previous
//
#include <hip/hip_runtime.h>

typedef unsigned short u16;
typedef __attribute__((ext_vector_type(8))) short short8;
typedef __attribute__((ext_vector_type(4))) float f32x4;

// Problem constants: B=2, T=2048, C=2048, H=16, HD=128
#define TSEQ 2048
#define NHEAD 16
#define HDIM 128

__device__ __forceinline__ u16 f2bf(float x) {
    unsigned u = __float_as_uint(x);
    return (u16)((u + 0x7fffu + ((u >> 16) & 1u)) >> 16);
}
__device__ __forceinline__ float b2f(u16 h) {
    return __uint_as_float(((unsigned)h) << 16);
}
__device__ __forceinline__ void async16(const void* g, void* l) {
    __builtin_amdgcn_global_load_lds((__attribute__((address_space(1))) void*)(void*)g,
                                     (__attribute__((address_space(3))) void*)l, 16, 0, 0);
}
__device__ __forceinline__ f32x4 zero4() {
    f32x4 z = {0.f, 0.f, 0.f, 0.f};
    return z;
}

// DPP cross-lane (16-lane group reductions), no LDS traffic
template <int CTRL>
__device__ __forceinline__ float dppf(float x) {
    return __int_as_float(__builtin_amdgcn_mov_dpp(__float_as_int(x), CTRL, 0xf, 0xf, true));
}
__device__ __forceinline__ float dpp_max16(float x) {
    x = fmaxf(x, dppf<0xB1>(x));   // quad_perm xor1
    x = fmaxf(x, dppf<0x4E>(x));   // quad_perm xor2
    x = fmaxf(x, dppf<0x141>(x));  // row_half_mirror (~xor4)
    x = fmaxf(x, dppf<0x140>(x));  // row_mirror (~xor8)
    return x;
}
__device__ __forceinline__ float dpp_sum16(float x) {
    x += dppf<0xB1>(x);
    x += dppf<0x4E>(x);
    x += dppf<0x141>(x);
    x += dppf<0x140>(x);
    return x;
}

// ---------------- cast x (f32 -> bf16), vectorized ----------------
__global__ void cast_bf16(const float4* __restrict__ in, ushort4* __restrict__ out, int n4) {
    int i = blockIdx.x * 256 + threadIdx.x;
    if (i < n4) {
        float4 v = in[i];
        ushort4 o;
        o.x = f2bf(v.x); o.y = f2bf(v.y); o.z = f2bf(v.z); o.w = f2bf(v.w);
        out[i] = o;
    }
}

// ---------------- transpose + cast: in f32 [K][N] -> out bf16 [N][K] ----------------
__global__ void transpose_cast(const float* __restrict__ in, u16* __restrict__ out, int K, int N) {
    __shared__ float tile[64][65];
    int n0 = blockIdx.x * 64, k0 = blockIdx.y * 64;
    int tx = threadIdx.x & 63, ty = threadIdx.x >> 6;
#pragma unroll
    for (int i = 0; i < 16; i++) {
        int r = ty + i * 4;
        tile[r][tx] = in[(size_t)(k0 + r) * N + n0 + tx];
    }
    __syncthreads();
#pragma unroll
    for (int i = 0; i < 16; i++) {
        int r = ty + i * 4;
        out[(size_t)(n0 + r) * K + k0 + tx] = f2bf(tile[tx][r]);
    }
}

// ---------------- GEMM: C = A(MxK) * Bt(NxK)^T + bias ----------------
// MODE 0: n-tile == one head (HDIM=128). LDS-transpose epilogue, fused RoPE
//         for q/k, v written transposed to vT [bh][d][t].
// MODE 1: f32 out row-major [M][N]
// NOTE: plain launch_bounds — (256,5) forced VGPR=48 + scratch spills (R4:
// WRITE_SIZE 49->126 MB). Never cap below the 64-VGPR accumulator.
template <int MODE>
__global__ __launch_bounds__(256) void gemm_bt(
    const u16* __restrict__ A, const u16* __restrict__ Bt, const float* __restrict__ bias,
    float* __restrict__ outf, u16* __restrict__ qb, u16* __restrict__ kb, u16* __restrict__ vT,
    const float* __restrict__ cosp, const float* __restrict__ sinp,
    int M, int N, int K) {
    __shared__ __align__(16) u16 smem[8704];  // 17408 B: staging (16K) / epilogue tile [64][136]
    u16* As = smem;            // 128*32 u16
    u16* Bs = smem + 4096;     // 128*32 u16
    const int tid = threadIdx.x;
    const int wave = tid >> 6, lane = tid & 63;
    const int low = lane & 15, quad = lane >> 4;
    const int m0 = blockIdx.y * 128, n0 = blockIdx.x * 128;
    const int wm = (wave >> 1) * 64, wn = (wave & 1) * 64;
    const int ldr = lane >> 2;
    const int ldc = (lane & 3) * 8;

    f32x4 acc[4][4];
#pragma unroll
    for (int i = 0; i < 4; i++)
#pragma unroll
        for (int j = 0; j < 4; j++) acc[i][j] = zero4();

    for (int k0 = 0; k0 < K; k0 += 32) {
#pragma unroll
        for (int c = 0; c < 2; ++c) {
            const int chunk = wave * 2 + c;
            const int row = chunk * 16 + ldr;
            async16(A + (size_t)(m0 + row) * K + k0 + ldc, As + chunk * 512);
            async16(Bt + (size_t)(n0 + row) * K + k0 + ldc, Bs + chunk * 512);
        }
        __syncthreads();
        short8 af[4], bfv[4];
#pragma unroll
        for (int i = 0; i < 4; i++) af[i] = *(const short8*)(As + (wm + i * 16 + low) * 32 + quad * 8);
#pragma unroll
        for (int j = 0; j < 4; j++) bfv[j] = *(const short8*)(Bs + (wn + j * 16 + low) * 32 + quad * 8);
#pragma unroll
        for (int i = 0; i < 4; i++)
#pragma unroll
            for (int j = 0; j < 4; j++)
                acc[i][j] = __builtin_amdgcn_mfma_f32_16x16x32_bf16(af[i], bfv[j], acc[i][j], 0, 0, 0);
        __syncthreads();
    }

    if (MODE == 1) {
#pragma unroll
        for (int j = 0; j < 4; j++) {
            const int ng = n0 + wn + j * 16 + low;
            const float bv = bias[ng];
#pragma unroll
            for (int i = 0; i < 4; i++) {
                const int rbase = m0 + wm + i * 16 + quad * 4;
#pragma unroll
                for (int r = 0; r < 4; r++)
                    outf[(size_t)(rbase + r) * N + ng] = acc[i][j][r] + bv;
            }
        }
        return;
    }

    // ---- MODE 0 epilogue ----
    const int which = n0 >> 11;                // 0=q 1=k 2=v
    const int h = (n0 & 2047) >> 7;
    const int b = m0 >> 11, t0 = m0 & 2047;
    float bv[4];
#pragma unroll
    for (int j = 0; j < 4; j++) bv[j] = bias[n0 + wn + j * 16 + low];
    u16* epi = smem;  // [64][136] bf16

    if (which < 2) {
        // q or k: [bh][t][d] contiguous tile, rope fused
        u16* dst = (which == 0 ? qb : kb) + (((size_t)(b * NHEAD + h)) * TSEQ + t0) * HDIM;
#pragma unroll
        for (int pass = 0; pass < 2; pass++) {
            if ((wave >> 1) == pass) {
#pragma unroll
                for (int i = 0; i < 4; i++)
#pragma unroll
                    for (int j = 0; j < 4; j++)
#pragma unroll
                        for (int r = 0; r < 4; r++)
                            epi[(i * 16 + quad * 4 + r) * 136 + wn + j * 16 + low] =
                                f2bf(acc[i][j][r] + bv[j]);
            }
            __syncthreads();
            const int row = tid >> 2, dq = tid & 3;
            const int t = t0 + pass * 64 + row;
            const float* cb = cosp + (size_t)t * 64 + dq * 16;
            const float* sb = sinp + (size_t)t * 64 + dq * 16;
            const u16* er = epi + row * 136 + dq * 32;
            u16* dr = dst + (size_t)(pass * 64 + row) * HDIM + dq * 32;
#pragma unroll
            for (int half = 0; half < 2; half++) {
                u16 vals[16];
                *(short8*)(vals) = *(const short8*)(er + half * 16);
                *(short8*)(vals + 8) = *(const short8*)(er + half * 16 + 8);
                float cs[8], sn[8];
                *(float4*)(cs) = *(const float4*)(cb + half * 8);
                *(float4*)(cs + 4) = *(const float4*)(cb + half * 8 + 4);
                *(float4*)(sn) = *(const float4*)(sb + half * 8);
                *(float4*)(sn + 4) = *(const float4*)(sb + half * 8 + 4);
                u16 ov[16];
#pragma unroll
                for (int p = 0; p < 8; p++) {
                    float x0 = b2f(vals[2 * p]), x1 = b2f(vals[2 * p + 1]);
                    ov[2 * p] = f2bf(x0 * cs[p] - x1 * sn[p]);
                    ov[2 * p + 1] = f2bf(x0 * sn[p] + x1 * cs[p]);
                }
                *(short8*)(dr + half * 16) = *(const short8*)(ov);
                *(short8*)(dr + half * 16 + 8) = *(const short8*)(ov + 8);
            }
            __syncthreads();
        }
    } else {
        // v: write transposed [bh][d][t]; LDS tile holds [d-rel 64][t 128+pad]
        u16* dst = vT + ((size_t)(b * NHEAD + h)) * HDIM * TSEQ + t0;
#pragma unroll
        for (int pass = 0; pass < 2; pass++) {
            if ((wave & 1) == pass) {  // wn == pass*64
#pragma unroll
                for (int i = 0; i < 4; i++)
#pragma unroll
                    for (int j = 0; j < 4; j++)
#pragma unroll
                        for (int r = 0; r < 4; r++)
                            epi[(j * 16 + low) * 136 + wm + i * 16 + quad * 4 + r] =
                                f2bf(acc[i][j][r] + bv[j]);
            }
            __syncthreads();
            const int drow = tid >> 2, tc = (tid & 3) * 32;
            u16* dr = dst + (size_t)(pass * 64 + drow) * TSEQ + tc;
#pragma unroll
            for (int q = 0; q < 4; q++)
                *(short8*)(dr + q * 8) = *(const short8*)(epi + drow * 136 + tc + q * 8);
            __syncthreads();
        }
    }
}

// ---------------- Flash attention v4 ----------------
// grid (x=bh, y=qt): XCD = bh%8 -> each XCD's L2 holds 4 heads' K+V (4 MB).
// K and V double-buffered; ONE barrier per tile; prefetch issued right after
// the barrier so the whole tile body hides the load latency. kf/vf LDS reads
// shared between the wave's two q-tiles; P fragments preloaded to registers.
__global__ __launch_bounds__(256, 2) void flash_attn(const u16* __restrict__ qg, const u16* __restrict__ kg,
                                                     const u16* __restrict__ vT, u16* __restrict__ y) {
    __shared__ u16 Ks[2][64 * 128];  // 32 KB [key][d], chunks xor-swizzled by (key&7)
    __shared__ u16 Vs[2][128 * 64];  // 32 KB [d][key], chunks xor-swizzled by (d&7)
    __shared__ u16 Ps[4][16 * 72];   // 9 KB per-wave P 16x64, row stride 72
    const int tid = threadIdx.x;
    const int wave = tid >> 6, lane = tid & 63;
    const int low = lane & 15, quad = lane >> 4;
    const int bh = blockIdx.x;       // XCD affinity: bh % 8
    const int qt = 15 - blockIdx.y;  // longest first
    const int qa = qt * 128 + wave * 16;
    const int qbr = qa + 64;
    const float scale2 = 0.08838834764831845f * 1.44269504088896f;  // 1/sqrt(128)*log2(e)

    const u16* Qp = qg + (size_t)bh * TSEQ * HDIM;
    short8 qfA[4], qfB[4];
#pragma unroll
    for (int c = 0; c < 4; c++) {
        qfA[c] = *(const short8*)(Qp + (size_t)(qa + low) * HDIM + c * 32 + quad * 8);
        qfB[c] = *(const short8*)(Qp + (size_t)(qbr + low) * HDIM + c * 32 + quad * 8);
    }

    f32x4 oA[8], oB[8];
#pragma unroll
    for (int d = 0; d < 8; d++) { oA[d] = zero4(); oB[d] = zero4(); }
    float mA[4], lA[4], mB[4], lB[4];
#pragma unroll
    for (int r = 0; r < 4; r++) { mA[r] = -1e30f; lA[r] = 0.f; mB[r] = -1e30f; lB[r] = 0.f; }

    const u16* Kb = kg + (size_t)bh * TSEQ * HDIM;
    const u16* Vb = vT + (size_t)bh * HDIM * TSEQ;
    u16* Pw = &Ps[wave][0];
    const int ntiles = 2 * qt + 2;

    const int krow = tid >> 4, kchunk = tid & 15;  // K: 16 rows x 16 chunks per issue
    const int vrow = tid >> 3, vchunk = tid & 7;   // V: 32 rows x 8 chunks per issue

    // prologue: stage tile 0 -> buffer 0
#pragma unroll
    for (int j = 0; j < 4; j++) {
        const int row = j * 16 + krow;
        async16(Kb + (size_t)row * HDIM + (kchunk ^ (row & 7)) * 8, Ks[0] + row * 128 + kchunk * 8);
    }
#pragma unroll
    for (int j = 0; j < 4; j++) {
        const int d = j * 32 + vrow;
        async16(Vb + (size_t)d * TSEQ + (vchunk ^ (d & 7)) * 8, Vs[0] + d * 64 + vchunk * 8);
    }

    for (int kt = 0; kt < ntiles; ++kt) {
        const int kv0 = kt * 64;
        const int cur = kt & 1;
        __syncthreads();  // drains tile-kt loads; buf[cur^1] safe to overwrite (last read kt-1)

        if (kt + 1 < ntiles) {
            const int nkv = kv0 + 64;
            u16* kd = Ks[cur ^ 1];
            u16* vd = Vs[cur ^ 1];
#pragma unroll
            for (int j = 0; j < 4; j++) {
                const int row = j * 16 + krow;
                async16(Kb + (size_t)(nkv + row) * HDIM + (kchunk ^ (row & 7)) * 8,
                        kd + row * 128 + kchunk * 8);
            }
#pragma unroll
            for (int j = 0; j < 4; j++) {
                const int d = j * 32 + vrow;
                async16(Vb + (size_t)d * TSEQ + nkv + (vchunk ^ (d & 7)) * 8, vd + d * 64 + vchunk * 8);
            }
        }

        const u16* Kc = Ks[cur];
        const u16* Vc = Vs[cur];
        const bool activeA = (kv0 <= qa + 15);

        // ---- QK^T for both q-tiles, kf loaded once ----
        f32x4 sA[4], sB[4];
#pragma unroll
        for (int h = 0; h < 4; h++) { sA[h] = zero4(); sB[h] = zero4(); }
#pragma unroll
        for (int h = 0; h < 4; h++) {
            const int row = h * 16 + low;
#pragma unroll
            for (int c = 0; c < 4; c++) {
                short8 kf = *(const short8*)(Kc + row * 128 + (((c * 4 + quad) ^ (row & 7))) * 8);
                sA[h] = __builtin_amdgcn_mfma_f32_16x16x32_bf16(qfA[c], kf, sA[h], 0, 0, 0);
                sB[h] = __builtin_amdgcn_mfma_f32_16x16x32_bf16(qfB[c], kf, sB[h], 0, 0, 0);
            }
        }

        short8 pfA[2], pfB[2];
        float alA[4], alB[4];
        // ---- softmax A ----
        if (activeA) {
#pragma unroll
            for (int r = 0; r < 4; r++) {
                const int qrow = qa + quad * 4 + r;
                float sv[4];
#pragma unroll
                for (int h = 0; h < 4; h++)
                    sv[h] = (kv0 + h * 16 + low <= qrow) ? sA[h][r] * scale2 : -1e30f;
                float mx = fmaxf(fmaxf(sv[0], sv[1]), fmaxf(sv[2], sv[3]));
                mx = dpp_max16(mx);
                float mnew = fmaxf(mA[r], mx);
                alA[r] = exp2f(mA[r] - mnew);
                mA[r] = mnew;
                float p0 = exp2f(sv[0] - mnew), p1 = exp2f(sv[1] - mnew);
                float p2 = exp2f(sv[2] - mnew), p3 = exp2f(sv[3] - mnew);
                float rs = (p0 + p1) + (p2 + p3);
                rs = dpp_sum16(rs);
                lA[r] = lA[r] * alA[r] + rs;
                const int prow = (quad * 4 + r) * 72;
                Pw[prow + low] = f2bf(p0);
                Pw[prow + 16 + low] = f2bf(p1);
                Pw[prow + 32 + low] = f2bf(p2);
                Pw[prow + 48 + low] = f2bf(p3);
            }
            __threadfence_block();  // cross-lane LDS visibility within wave
#pragma unroll
            for (int kc = 0; kc < 2; kc++)
                pfA[kc] = *(const short8*)(Pw + low * 72 + kc * 32 + quad * 8);
        }
        // ---- softmax B (reuses Pw; per-wave DS ops are in-order) ----
        {
#pragma unroll
            for (int r = 0; r < 4; r++) {
                const int qrow = qbr + quad * 4 + r;
                float sv[4];
#pragma unroll
                for (int h = 0; h < 4; h++)
                    sv[h] = (kv0 + h * 16 + low <= qrow) ? sB[h][r] * scale2 : -1e30f;
                float mx = fmaxf(fmaxf(sv[0], sv[1]), fmaxf(sv[2], sv[3]));
                mx = dpp_max16(mx);
                float mnew = fmaxf(mB[r], mx);
                alB[r] = exp2f(mB[r] - mnew);
                mB[r] = mnew;
                float p0 = exp2f(sv[0] - mnew), p1 = exp2f(sv[1] - mnew);
                float p2 = exp2f(sv[2] - mnew), p3 = exp2f(sv[3] - mnew);
                float rs = (p0 + p1) + (p2 + p3);
                rs = dpp_sum16(rs);
                lB[r] = lB[r] * alB[r] + rs;
                const int prow = (quad * 4 + r) * 72;
                Pw[prow + low] = f2bf(p0);
                Pw[prow + 16 + low] = f2bf(p1);
                Pw[prow + 32 + low] = f2bf(p2);
                Pw[prow + 48 + low] = f2bf(p3);
            }
            __threadfence_block();
#pragma unroll
            for (int kc = 0; kc < 2; kc++)
                pfB[kc] = *(const short8*)(Pw + low * 72 + kc * 32 + quad * 8);
        }

        // ---- rescale + merged PV (vf loaded once) ----
        if (activeA) {
#pragma unroll
            for (int d = 0; d < 8; ++d)
#pragma unroll
                for (int r = 0; r < 4; r++) { oA[d][r] *= alA[r]; oB[d][r] *= alB[r]; }
#pragma unroll
            for (int kc = 0; kc < 2; kc++)
#pragma unroll
                for (int dd = 0; dd < 8; ++dd) {
                    const int vr = dd * 16 + low;
                    short8 vf = *(const short8*)(Vc + vr * 64 + (((kc * 4 + quad) ^ (vr & 7))) * 8);
                    oA[dd] = __builtin_amdgcn_mfma_f32_16x16x32_bf16(pfA[kc], vf, oA[dd], 0, 0, 0);
                    oB[dd] = __builtin_amdgcn_mfma_f32_16x16x32_bf16(pfB[kc], vf, oB[dd], 0, 0, 0);
                }
        } else {
#pragma unroll
            for (int d = 0; d < 8; ++d)
#pragma unroll
                for (int r = 0; r < 4; r++) oB[d][r] *= alB[r];
#pragma unroll
            for (int kc = 0; kc < 2; kc++)
#pragma unroll
                for (int dd = 0; dd < 8; ++dd) {
                    const int vr = dd * 16 + low;
                    short8 vf = *(const short8*)(Vc + vr * 64 + (((kc * 4 + quad) ^ (vr & 7))) * 8);
                    oB[dd] = __builtin_amdgcn_mfma_f32_16x16x32_bf16(pfB[kc], vf, oB[dd], 0, 0, 0);
                }
        }
    }

    const int b = bh >> 4, h = bh & 15;
#pragma unroll
    for (int r = 0; r < 4; r++) {
        float invA = 1.0f / lA[r];
        float invB = 1.0f / lB[r];
        size_t rowA = (size_t)(b * TSEQ + qa + quad * 4 + r);
        size_t rowB = (size_t)(b * TSEQ + qbr + quad * 4 + r);
        u16* ypA = y + rowA * 2048 + h * HDIM;
        u16* ypB = y + rowB * 2048 + h * HDIM;
#pragma unroll
        for (int d = 0; d < 8; ++d) {
            ypA[d * 16 + low] = f2bf(oA[d][r] * invA);
            ypB[d * 16 + low] = f2bf(oB[d][r] * invB);
        }
    }
}

extern "C" void kernel_launch(void* const* d_in, const int* in_sizes, int n_in,
                              void* d_out, int out_size, void* d_ws, size_t ws_size,
                              hipStream_t stream) {
    const float* x = (const float*)d_in[0];
    const float* Wa = (const float*)d_in[1];
    const float* ba = (const float*)d_in[2];
    const float* Wp = (const float*)d_in[3];
    const float* bp = (const float*)d_in[4];
    const float* cs = (const float*)d_in[5];
    const float* sn = (const float*)d_in[6];
    float* out = (float*)d_out;

    u16* xb = (u16*)d_ws;             // x bf16; reused later as y
    u16* Wab = xb + 8388608;          // W_attn^T bf16 [6144][2048]
    u16* Wpb = Wab + 12582912;        // W_proj^T bf16 [2048][2048]
    u16* qb = Wpb + 4194304;          // [bh][t][d]
    u16* kb = qb + 8388608;           // [bh][t][d]
    u16* vT = kb + 8388608;           // [bh][d][t]
    u16* y = xb;

    cast_bf16<<<8192, 256, 0, stream>>>((const float4*)x, (ushort4*)xb, 2097152);
    transpose_cast<<<dim3(96, 32), 256, 0, stream>>>(Wa, Wab, 2048, 6144);
    transpose_cast<<<dim3(32, 32), 256, 0, stream>>>(Wp, Wpb, 2048, 2048);
    gemm_bt<0><<<dim3(48, 32), 256, 0, stream>>>(xb, Wab, ba, nullptr, qb, kb, vT, cs, sn, 4096, 6144, 2048);
    flash_attn<<<dim3(32, 16), 256, 0, stream>>>(qb, kb, vT, y);
    gemm_bt<1><<<dim3(16, 32), 256, 0, stream>>>(y, Wpb, bp, out, nullptr, nullptr, nullptr, nullptr, nullptr, 4096, 2048, 2048);
}